// Round 3
// baseline (620.510 us; speedup 1.0000x reference)
//
#include <hip/hip_runtime.h>
#include <math.h>

#ifndef M_PI
#define M_PI 3.14159265358979323846
#endif

#define TPB 256
// LDS bank swizzle at 16B granularity: bijective on [0,2048); for every
// lane-stride used here (1,2,8,32,512-scatter) maps 8 consecutive lanes to 8
// distinct bank-quads -> conflict-free ds_read_b128 (hand-verified per stride).
#define IDX(i) ((i) ^ (((i) >> 3) & 7) ^ (((i) >> 6) & 7) ^ (((i) >> 9) & 7))

// Digit-reverse for 2048 = 4^5 * 2, radix sequence [4,4,4,4,4,2] (DIF order).
__device__ __forceinline__ int drev11(int k) {
  return ((k & 3) << 9) | (((k >> 2) & 3) << 7) | (((k >> 4) & 3) << 5)
       | (((k >> 6) & 3) << 3) | (((k >> 8) & 3) << 1) | ((k >> 10) & 1);
}

// W_4096^k = e^{-i*pi*k/2048}, k in [0,2048]; Cc[m] = cos(pi*m/2048), m<=1025.
__device__ __forceinline__ void wn4096c(int k, const double* Cc,
                                        double& wr, double& wi) {
  int q = k >> 9, r = k & 511;
  const double H = 0.7071067811865476;
  double pr  = (q == 0) ? 1.0 : (q == 1) ? H    : (q == 2) ? 0.0  : (q == 3) ? -H : -1.0;
  double pii = (q == 0) ? 0.0 : (q == 1) ? -H   : (q == 2) ? -1.0 : (q == 3) ? -H : 0.0;
  double ur = Cc[r], ui = -Cc[1024 - r];   // cos, -sin
  wr = pr * ur - pii * ui;
  wi = pr * ui + pii * ur;
}

// |X[k]|^2 in fp64 from the digit-reversed, swizzled packed spectrum Z.
__device__ __forceinline__ double exactMag2(int k, const double2* Z,
                                            const double* Cc) {
  int ka = k & 2047, kb = (2048 - k) & 2047;
  double2 za = Z[IDX(drev11(ka))], zb = Z[IDX(drev11(kb))];
  double her = 0.5 * (za.x + zb.x), hei = 0.5 * (za.y - zb.y);
  double hor = 0.5 * (za.y + zb.y), hoi = -0.5 * (za.x - zb.x);
  double wr, wi; wn4096c(k, Cc, wr, wi);
  double xr = her + wr * hor - wi * hoi;
  double xi = hei + wr * hoi + wi * hor;
  return xr * xr + xi * xi;
}

// Build Cc[m] = cos(pi*m/2048), m in [0,1025], in global ws (once per launch).
__global__ void twid_build(double* __restrict__ Cg) {
  int m = blockIdx.x * 256 + threadIdx.x;
  if (m < 1026) Cg[m] = cos((M_PI / 2048.0) * (double)m);
}

// One block per (b,c) signal, fused strided I/O on (B,S,C) layout:
// fp64 packed rfft -> top-k mask -> fp32 irfft.
__global__ __launch_bounds__(TPB, 3) void fourier_topk_kernel(
    const float* __restrict__ src, float* __restrict__ dst,
    const int* __restrict__ kptr, const double* __restrict__ Cg) {
  __shared__ double2 Z[2048];                    // 32 KB interleaved (re,im)
  __shared__ double Cc[1026];                    // 8.2 KB quarter-wave cos table
  __shared__ float keyF[2049];                   // 8.2 KB
  __shared__ unsigned int hist[256];
  __shared__ unsigned char maskA[2052];
  __shared__ int tieIdx[64];
  __shared__ unsigned int bcD, bcR, bcCnt, bcT, bcG, bcE, bcTieN;

  const int tid = threadIdx.x;
  // XCD swizzle: XCD j (blockIdx%8) owns channels [16j,16j+16) for ALL batches
  // -> each 64B line (16 channels) lives on exactly one XCD's L2; the 16
  // sibling blocks per line-set are dispatch-consecutive -> co-resident.
  int i = blockIdx.x;
  int xj = i & 7, mm = i >> 3;
  int c = 16 * xj + (mm & 15);
  int b = mm >> 4;
  const size_t base = (size_t)b * 4096 * 128 + (size_t)c;
  const float* sp = src + base;
  float* dp = dst + base;

  // Stage strided input into registers first (16 outstanding loads/thread).
  float xv[16];
#pragma unroll
  for (int it = 0; it < 8; ++it) {
    int n = tid + 256 * it;
    xv[2 * it]     = sp[(size_t)(2 * n) * 128];
    xv[2 * it + 1] = sp[(size_t)(2 * n + 1) * 128];
  }
  // Twiddle table while loads are in flight.
  if (Cg) { for (int m = tid; m < 1026; m += TPB) Cc[m] = Cg[m]; }
  else    { for (int m = tid; m < 1026; m += TPB) Cc[m] = cos((M_PI / 2048.0) * (double)m); }
  // z[n] = x[2n] + i*x[2n+1]
#pragma unroll
  for (int it = 0; it < 8; ++it) {
    int n = tid + 256 * it;
    Z[IDX(n)] = make_double2((double)xv[2 * it], (double)xv[2 * it + 1]);
  }
  __syncthreads();

  // ---- forward FFT (fp64): in-place radix-4 DIF, natural -> digit-reversed ----
#pragma unroll
  for (int st = 0; st <= 4; ++st) {
    const int n = 2048 >> (2 * st);        // 2048,512,128,32,8
    const int lm = 9 - 2 * st;             // log2(mq)
    const int mq = 1 << lm;
#pragma unroll
    for (int uu = 0; uu < 2; ++uu) {
      int u = tid + uu * TPB;
      int blk, j;
      if (lm >= 4) { blk = u >> lm; j = u & (mq - 1); }
      else { int lnb = 9 - lm; blk = u & ((1 << lnb) - 1); j = u >> lnb; }
      int b4 = blk * n + j;
      int pa = IDX(b4), pb = IDX(b4 + mq), pc = IDX(b4 + 2 * mq), pd = IDX(b4 + 3 * mq);
      double2 A = Z[pa], Bv = Z[pb], Cv = Z[pc], Dv = Z[pd];
      double apcr = A.x + Cv.x, apci = A.y + Cv.y;
      double amcr = A.x - Cv.x, amci = A.y - Cv.y;
      double bpdr = Bv.x + Dv.x, bpdi = Bv.y + Dv.y;
      double bmdr = Bv.x - Dv.x, bmdi = Bv.y - Dv.y;
      Z[pa] = make_double2(apcr + bpdr, apci + bpdi);
      int ix = j << (2 * st);                                  // j*(2048/n) < 512
      double w1r = Cc[2 * ix], w1i = -Cc[1024 - 2 * ix];
      double w2r = w1r * w1r - w1i * w1i, w2i = 2.0 * w1r * w1i;
      double w3r = w2r * w1r - w2i * w1i, w3i = w2r * w1i + w2i * w1r;
      double t1r = amcr + bmdi, t1i = amci - bmdr;             // amc - i*bmd
      Z[pb] = make_double2(w1r * t1r - w1i * t1i, w1r * t1i + w1i * t1r);
      double t2r = apcr - bpdr, t2i = apci - bpdi;
      Z[pc] = make_double2(w2r * t2r - w2i * t2i, w2r * t2i + w2i * t2r);
      double t3r = amcr - bmdi, t3i = amci + bmdr;             // amc + i*bmd
      Z[pd] = make_double2(w3r * t3r - w3i * t3i, w3r * t3i + w3i * t3r);
    }
    __syncthreads();
  }
#pragma unroll
  for (int uu = 0; uu < 4; ++uu) {                             // final radix-2
    int u = tid + uu * TPB;
    int p0 = IDX(2 * u), p1 = IDX(2 * u + 1);
    double2 A = Z[p0], Bv = Z[p1];
    Z[p0] = make_double2(A.x + Bv.x, A.y + Bv.y);
    Z[p1] = make_double2(A.x - Bv.x, A.y - Bv.y);
  }
  __syncthreads();

  // ---- magnitude^2 keys (fp64 compute, fp32-rounded monotone keys) ----
  for (int k = tid; k <= 2048; k += TPB)
    keyF[k] = (float)exactMag2(k, Z, Cc);
  __syncthreads();

  // ---- top-k threshold via 4-pass 8-bit radix select on u32 keys ----
  int kk = kptr[0];
  if (kk > 2049) kk = 2049;
  if (kk < 1) kk = 1;
  unsigned int prefix = 0u, pmask = 0u, Tkey = 0u;
  bool haveT = false;
  int R = kk;
#pragma unroll 1
  for (int p = 0; p < 4; ++p) {
    if (!haveT) {  // uniform (haveT from LDS broadcast)
      const int sh = 24 - 8 * p;
      hist[tid] = 0u;
      __syncthreads();
      for (int k = tid; k <= 2048; k += TPB) {
        unsigned int u = __float_as_uint(keyF[k]);
        if ((u & pmask) == prefix) atomicAdd(&hist[(u >> sh) & 255u], 1u);
      }
      __syncthreads();
      // Single-wave suffix scan over 256 buckets (no barriers inside).
      if (tid < 64) {
        int L = tid;
        int s0 = (int)hist[4 * L], s1 = (int)hist[4 * L + 1];
        int s2 = (int)hist[4 * L + 2], s3 = (int)hist[4 * L + 3];
        int loc = s0 + s1 + s2 + s3;
        int suf = loc;
#pragma unroll
        for (int off = 1; off < 64; off <<= 1) {
          int t = __shfl(suf, (L + off) & 63, 64);
          suf += (L + off < 64) ? t : 0;
        }
        int e3 = suf - loc,  i3 = e3 + s3;   // bucket 4L+3 (highest in chunk)
        int e2 = i3,         i2 = e2 + s2;
        int e1 = i2,         i1 = e1 + s1;
        int e0 = i1,         i0 = e0 + s0;
        if (e3 < R && R <= i3) { bcD = 4 * L + 3; bcR = R - e3; bcCnt = s3; }
        if (e2 < R && R <= i2) { bcD = 4 * L + 2; bcR = R - e2; bcCnt = s2; }
        if (e1 < R && R <= i1) { bcD = 4 * L + 1; bcR = R - e1; bcCnt = s1; }
        if (e0 < R && R <= i0) { bcD = 4 * L + 0; bcR = R - e0; bcCnt = s0; }
      }
      __syncthreads();
      prefix |= (bcD << sh);
      pmask |= (255u << sh);
      R = (int)bcR;
      if (bcCnt == 1u) {                          // unique boundary element
        for (int k = tid; k <= 2048; k += TPB) {
          unsigned int u = __float_as_uint(keyF[k]);
          if ((u & pmask) == prefix) bcT = u;
        }
        __syncthreads();
        Tkey = bcT;
        haveT = true;
      }
      __syncthreads();
    }
  }
  if (!haveT) Tkey = prefix;

  // counts above / equal
  if (tid == 0) { bcG = 0u; bcE = 0u; bcTieN = 0u; }
  __syncthreads();
  for (int k = tid; k <= 2048; k += TPB) {
    unsigned int u = __float_as_uint(keyF[k]);
    if (u > Tkey) atomicAdd(&bcG, 1u);
    else if (u == Tkey) atomicAdd(&bcE, 1u);
  }
  __syncthreads();
  int need = kk - (int)bcG;
  int e = (int)bcE;
  if (need >= e) {   // common path: keep everything >= Tkey (exactly kk kept)
    for (int k = tid; k <= 2048; k += TPB)
      maskA[k] = (__float_as_uint(keyF[k]) >= Tkey) ? 1 : 0;
    __syncthreads();
  } else {           // rare: fp32 key collision at boundary -> exact fp64 tie-break
    for (int k = tid; k <= 2048; k += TPB) {
      unsigned int u = __float_as_uint(keyF[k]);
      maskA[k] = (u > Tkey) ? 1 : 0;
      if (u == Tkey) {
        int pos = (int)atomicAdd(&bcTieN, 1u);
        if (pos < 64) tieIdx[pos] = k;
      }
    }
    __syncthreads();
    if (tid == 0) {
      int nt = (int)bcTieN; if (nt > 64) nt = 64;
      double vals[64];
      unsigned char chosen[64];
      for (int t = 0; t < nt; ++t) { vals[t] = exactMag2(tieIdx[t], Z, Cc); chosen[t] = 0; }
      int lim = (need < 64) ? need : 64;
      for (int s = 0; s < lim; ++s) {
        int best = -1;
        for (int t = 0; t < nt; ++t) {
          if (chosen[t]) continue;
          if (best < 0 || vals[t] > vals[best] ||
              (vals[t] == vals[best] && tieIdx[t] < tieIdx[best])) best = t;
        }
        if (best >= 0) { chosen[best] = 1; maskA[tieIdx[best]] = 1; }
      }
    }
    __syncthreads();
  }

  // ---- filter + repack (fp64 math), result staged fp32 in registers ----
  float rfr[8], rfi[8];
#pragma unroll
  for (int jj = 0; jj < 8; ++jj) {
    int k = tid + TPB * jj;
    int kb = (2048 - k) & 2047;
    double2 za = Z[IDX(drev11(k))], zb = Z[IDX(drev11(kb))];
    double her = 0.5 * (za.x + zb.x), hei = 0.5 * (za.y - zb.y);
    double hor = 0.5 * (za.y + zb.y), hoi = -0.5 * (za.x - zb.x);
    double wr, wi; wn4096c(k, Cc, wr, wi);
    double whr = wr * hor - wi * hoi, whi = wr * hoi + wi * hor;   // W*Ho
    double x1r = her + whr, x1i = hei + whi;                        // X[k]
    double x2r = her - whr, x2i = -(hei - whi);                     // X[2048-k]
    double Am = maskA[k] ? 1.0 : 0.0, Bm = maskA[2048 - k] ? 1.0 : 0.0;
    double Ar2 = Am * x1r, Ai2 = Am * x1i;
    double Br2 = Bm * x2r, Bi2 = Bm * x2i;
    double sr_ = Ar2 + Br2, si_ = Ai2 - Bi2;                        // A + conj(B)
    double dr_ = Ar2 - Br2, di_ = Ai2 + Bi2;                        // A - conj(B)
    double tr_ = wr * dr_ + wi * di_, ti_ = wr * di_ - wi * dr_;    // conj(W)*(A-conj B)
    rfr[jj] = (float)(0.5 * (sr_ - ti_));
    rfi[jj] = (float)(0.5 * (si_ + tr_));
  }
  __syncthreads();

  // ---- inverse FFT in fp32 (interleaved float2 aliased into Z) ----
  float2* F = reinterpret_cast<float2*>(Z);
#pragma unroll
  for (int jj = 0; jj < 8; ++jj) {
    int k = tid + TPB * jj;
    F[IDX(drev11(k))] = make_float2(rfr[jj], rfi[jj]);
  }
  __syncthreads();
#pragma unroll
  for (int uu = 0; uu < 4; ++uu) {                               // radix-2 first
    int u = tid + uu * TPB;
    int p0 = IDX(2 * u), p1 = IDX(2 * u + 1);
    float2 A = F[p0], Bv = F[p1];
    F[p0] = make_float2(A.x + Bv.x, A.y + Bv.y);
    F[p1] = make_float2(A.x - Bv.x, A.y - Bv.y);
  }
  __syncthreads();
#pragma unroll
  for (int st = 4; st >= 0; --st) {
    const int n = 2048 >> (2 * st);        // 8,32,128,512,2048
    const int lm = 9 - 2 * st;
    const int mq = 1 << lm;
#pragma unroll
    for (int uu = 0; uu < 2; ++uu) {
      int u = tid + uu * TPB;
      int blk, j;
      if (lm >= 4) { blk = u >> lm; j = u & (mq - 1); }
      else { int lnb = 9 - lm; blk = u & ((1 << lnb) - 1); j = u >> lnb; }
      int b4 = blk * n + j;
      int pa = IDX(b4), pb = IDX(b4 + mq), pc = IDX(b4 + 2 * mq), pd = IDX(b4 + 3 * mq);
      float2 y0 = F[pa], y1 = F[pb], y2 = F[pc], y3 = F[pd];
      int ix = j << (2 * st);
      float w1r = (float)Cc[2 * ix], w1i = (float)Cc[1024 - 2 * ix];  // conj twiddle
      float w2r = w1r * w1r - w1i * w1i, w2i = 2.0f * w1r * w1i;
      float w3r = w2r * w1r - w2i * w1i, w3i = w2r * w1i + w2i * w1r;
      float F1r = w1r * y1.x - w1i * y1.y, F1i = w1r * y1.y + w1i * y1.x;
      float F2r = w2r * y2.x - w2i * y2.y, F2i = w2r * y2.y + w2i * y2.x;
      float F3r = w3r * y3.x - w3i * y3.y, F3i = w3r * y3.y + w3i * y3.x;
      float s02r = y0.x + F2r, s02i = y0.y + F2i;
      float d02r = y0.x - F2r, d02i = y0.y - F2i;
      float s13r = F1r + F3r, s13i = F1i + F3i;
      float d13r = F1r - F3r, d13i = F1i - F3i;
      F[pa] = make_float2(s02r + s13r, s02i + s13i);
      F[pb] = make_float2(d02r - d13i, d02i + d13r);    // +i*d13
      F[pc] = make_float2(s02r - s13r, s02i - s13i);
      F[pd] = make_float2(d02r + d13i, d02i - d13r);    // -i*d13
    }
    __syncthreads();
  }

  // ---- fused strided store (scale 1/2048 for unnormalized fwd/inv pair) ----
  const float scf = 1.0f / 2048.0f;
#pragma unroll
  for (int it = 0; it < 8; ++it) {
    int n = tid + 256 * it;
    float2 v = F[IDX(n)];
    dp[(size_t)(2 * n) * 128]     = v.x * scf;
    dp[(size_t)(2 * n + 1) * 128] = v.y * scf;
  }
}

extern "C" void kernel_launch(void* const* d_in, const int* in_sizes, int n_in,
                              void* d_out, int out_size, void* d_ws, size_t ws_size,
                              hipStream_t stream) {
  (void)in_sizes; (void)n_in; (void)out_size;
  const float* ts = (const float*)d_in[0];
  const int* kptr = (const int*)d_in[1];
  float* out = (float*)d_out;
  const size_t tabBytes = 1026 * sizeof(double);

  double* Cg = (ws_size >= tabBytes) ? (double*)d_ws : nullptr;
  if (Cg) twid_build<<<5, 256, 0, stream>>>(Cg);
  fourier_topk_kernel<<<64 * 128, TPB, 0, stream>>>(ts, out, kptr, Cg);
}

// Round 4
// 603.088 us; speedup vs baseline: 1.0289x; 1.0289x over previous
//
#include <hip/hip_runtime.h>
#include <math.h>

#define TPB 256
// LDS swizzle at float2 (8B) granularity, bijective on [0,2048). For every
// wave access pattern in this kernel (strides 1,4,32,256 and the digit-
// reversed scatter) each bank-quad is hit exactly 4x per 64-lane b64 access,
// which is the conflict-free minimum (128 words over 32 banks).
#define SWZ(i) ((i) ^ (((i) >> 5) & 31) ^ ((i) >> 10))

// Angle constants
#define A2048 0.0030679615757712823f   // 2*pi/2048
#define A256  0.0245436926061702596f   // 2*pi/256
#define A32   0.1963495408493620774f   // 2*pi/32
#define APACK 0.0015339807878856411f   // pi/2048
#define EPSB  1.220703125e-4f          // 2^-13 selection band

__device__ __forceinline__ float2 cadd(float2 a, float2 b){return make_float2(a.x+b.x, a.y+b.y);}
__device__ __forceinline__ float2 csub(float2 a, float2 b){return make_float2(a.x-b.x, a.y-b.y);}
__device__ __forceinline__ float2 cmul(float2 a, float2 b){return make_float2(a.x*b.x-a.y*b.y, a.x*b.y+a.y*b.x);}
__device__ __forceinline__ float2 cni(float2 a){return make_float2(a.y, -a.x);}   // -i*a
__device__ __forceinline__ float2 cpi(float2 a){return make_float2(-a.y, a.x);}   // +i*a

// After DIF stages with radices [8,8,8,4], frequency k sits at pos2048(k).
__device__ __forceinline__ int pos2048(int k) {
  return 256*(k&7) + 32*((k>>3)&7) + 4*((k>>6)&7) + ((k>>9)&3);
}

__device__ __forceinline__ void fft8(float2 y[8]) {
  const float S2 = 0.70710678118654752f;
  float2 B0=cadd(y[0],y[4]), B4=csub(y[0],y[4]);
  float2 B1=cadd(y[1],y[5]), B5=csub(y[1],y[5]);
  float2 B2=cadd(y[2],y[6]), B6=csub(y[2],y[6]);
  float2 B3=cadd(y[3],y[7]), B7=csub(y[3],y[7]);
  float2 C0=cadd(B0,B2), C2=csub(B0,B2);
  float2 C1=cadd(B1,B3), C3=csub(B1,B3);
  float2 n6=cni(B6), n7=cni(B7);
  float2 C4=cadd(B4,n6), C6=csub(B4,n6);
  float2 C5=cadd(B5,n7), C7=csub(B5,n7);
  y[0]=cadd(C0,C1); y[4]=csub(C0,C1);
  float2 n3=cni(C3);
  y[2]=cadd(C2,n3); y[6]=csub(C2,n3);
  float2 t5=make_float2(S2*(C5.x+C5.y), S2*(C5.y-C5.x));       // w8*C5
  y[1]=cadd(C4,t5); y[5]=csub(C4,t5);
  float2 t7=make_float2(S2*(C7.y-C7.x), -S2*(C7.x+C7.y));      // w8^3*C7
  y[3]=cadd(C6,t7); y[7]=csub(C6,t7);
}

__device__ __forceinline__ void ifft8(float2 y[8]) {
  const float S2 = 0.70710678118654752f;
  float2 B0=cadd(y[0],y[4]), B4=csub(y[0],y[4]);
  float2 B1=cadd(y[1],y[5]), B5=csub(y[1],y[5]);
  float2 B2=cadd(y[2],y[6]), B6=csub(y[2],y[6]);
  float2 B3=cadd(y[3],y[7]), B7=csub(y[3],y[7]);
  float2 C0=cadd(B0,B2), C2=csub(B0,B2);
  float2 C1=cadd(B1,B3), C3=csub(B1,B3);
  float2 p6=cpi(B6), p7=cpi(B7);
  float2 C4=cadd(B4,p6), C6=csub(B4,p6);
  float2 C5=cadd(B5,p7), C7=csub(B5,p7);
  y[0]=cadd(C0,C1); y[4]=csub(C0,C1);
  float2 p3=cpi(C3);
  y[2]=cadd(C2,p3); y[6]=csub(C2,p3);
  float2 t5=make_float2(S2*(C5.x-C5.y), S2*(C5.x+C5.y));       // conj(w8)*C5
  y[1]=cadd(C4,t5); y[5]=csub(C4,t5);
  float2 t7=make_float2(-S2*(C7.x+C7.y), S2*(C7.x-C7.y));      // conj(w8)^3*C7
  y[3]=cadd(C6,t7); y[7]=csub(C6,t7);
}

// One radix-8 stage: DIF fwd = butterfly then twiddle W^(j*s); DIT inv =
// conj-twiddle then inverse butterfly. a1 carries the sign.
__device__ __forceinline__ void r8stage(float2* Zf, int idx0, int st, float a1, bool inv) {
  float2 y[8];
#pragma unroll
  for (int s=0;s<8;++s) y[s]=Zf[SWZ(idx0+st*s)];
  float sn, cs; __sincosf(a1, &sn, &cs);
  float2 w1=make_float2(cs,sn);
  float2 w2=cmul(w1,w1), w3=cmul(w2,w1), w4=cmul(w2,w2);
  float2 w5=cmul(w4,w1), w6=cmul(w4,w2), w7=cmul(w4,w3);
  if (inv){
    y[1]=cmul(y[1],w1); y[2]=cmul(y[2],w2); y[3]=cmul(y[3],w3);
    y[4]=cmul(y[4],w4); y[5]=cmul(y[5],w5); y[6]=cmul(y[6],w6); y[7]=cmul(y[7],w7);
    ifft8(y);
  } else {
    fft8(y);
    y[1]=cmul(y[1],w1); y[2]=cmul(y[2],w2); y[3]=cmul(y[3],w3);
    y[4]=cmul(y[4],w4); y[5]=cmul(y[5],w5); y[6]=cmul(y[6],w6); y[7]=cmul(y[7],w7);
  }
#pragma unroll
  for (int s=0;s<8;++s) Zf[SWZ(idx0+st*s)] = y[s];
}

// (B, R, Cd) -> (B, Cd, R) transpose, 64x64 tiles, float4 on both sides.
__global__ __launch_bounds__(256) void tposeV(const float* __restrict__ in,
                                              float* __restrict__ out,
                                              int R, int Cd) {
  __shared__ float tile[64][65];
  int t = threadIdx.x;
  int q = t & 15, r = t >> 4;
  int b = blockIdx.z;
  int c0 = blockIdx.x * 64, r0 = blockIdx.y * 64;
  const float4* in4 = reinterpret_cast<const float4*>(in + (size_t)b * R * Cd);
  float4* out4 = reinterpret_cast<float4*>(out + (size_t)b * R * Cd);
#pragma unroll
  for (int rr = r; rr < 64; rr += 16) {
    float4 v = in4[((size_t)(r0 + rr) * Cd + c0) / 4 + q];
    tile[rr][4 * q + 0] = v.x; tile[rr][4 * q + 1] = v.y;
    tile[rr][4 * q + 2] = v.z; tile[rr][4 * q + 3] = v.w;
  }
  __syncthreads();
#pragma unroll
  for (int cc = r; cc < 64; cc += 16) {
    float4 w;
    w.x = tile[4 * q + 0][cc]; w.y = tile[4 * q + 1][cc];
    w.z = tile[4 * q + 2][cc]; w.w = tile[4 * q + 3][cc];
    out4[((size_t)(c0 + cc) * R + r0) / 4 + q] = w;
  }
}

// One block per (b,c) signal: fp32 packed rfft (radix-8 register-resident) ->
// top-k via fp32 radix-select + band + exact fp64 DFT recheck -> fp32 irfft.
__global__ __launch_bounds__(TPB, 4) void fourier_topk_kernel(
    const float* __restrict__ src, float* __restrict__ dst,
    const int* __restrict__ kptr, int strideT) {
  __shared__ float2 Zf[2048];            // 16 KB
  __shared__ unsigned int hist[256];
  __shared__ unsigned int scanB[256];
  __shared__ unsigned char maskA[2052];
  __shared__ int tieIdx[64];
  __shared__ double candV[64];
  __shared__ double cpR[4], cpI[4];
  __shared__ unsigned int bcD, bcR, bcCnt, bcT, bcG, bcTieN;

  const int tid = threadIdx.x;
  int i = blockIdx.x;
  int xj = i & 7, mm = i >> 3;
  int c = 16 * xj + (mm & 15);
  int b = mm >> 4;
  const size_t base = (strideT == 1) ? ((size_t)(b * 128 + c)) * 4096
                                     : ((size_t)b * 4096 * 128 + (size_t)c);
  const float* sp = src + base;
  float* dp = dst + base;

  // ---- load; keep raw samples in registers for the fp64 DFT recheck ----
  float xs[16];
  if (strideT == 1) {
    const float4* sp4 = reinterpret_cast<const float4*>(sp);
#pragma unroll
    for (int it = 0; it < 4; ++it) {
      int t4 = tid + 256 * it;
      float4 v = sp4[t4];
      xs[4*it] = v.x; xs[4*it+1] = v.y; xs[4*it+2] = v.z; xs[4*it+3] = v.w;
      Zf[SWZ(2*t4)]   = make_float2(v.x, v.y);
      Zf[SWZ(2*t4+1)] = make_float2(v.z, v.w);
    }
  } else {
#pragma unroll
    for (int it = 0; it < 8; ++it) {
      int n = tid + 256 * it;
      float a = sp[(size_t)(2*n) * strideT];
      float bb = sp[(size_t)(2*n+1) * strideT];
      xs[2*it] = a; xs[2*it+1] = bb;
      Zf[SWZ(n)] = make_float2(a, bb);
    }
  }
  __syncthreads();

  // ---- forward FFT: radices [8,8,8,4], natural -> pos2048 order ----
  r8stage(Zf, tid, 256, -A2048 * (float)tid, false);
  __syncthreads();
  r8stage(Zf, 256*(tid>>5) + (tid&31), 32, -A256 * (float)(tid&31), false);
  __syncthreads();
  r8stage(Zf, 32*(tid>>2) + (tid&3), 4, -A32 * (float)(tid&3), false);
  __syncthreads();
#pragma unroll
  for (int h = 0; h < 2; ++h) {          // final radix-4, no twiddle
    int i0 = 4 * (tid + 256*h);
    float2 A0=Zf[SWZ(i0)], A1=Zf[SWZ(i0+1)], A2=Zf[SWZ(i0+2)], A3=Zf[SWZ(i0+3)];
    float2 f=cadd(A0,A2), e=csub(A0,A2), g=cadd(A1,A3), d=csub(A1,A3);
    float2 nd=cni(d);
    Zf[SWZ(i0)]   = cadd(f,g);
    Zf[SWZ(i0+1)] = cadd(e,nd);
    Zf[SWZ(i0+2)] = csub(f,g);
    Zf[SWZ(i0+3)] = csub(e,nd);
  }
  __syncthreads();

  // ---- fp32 magnitude^2 keys (registers; thread 0 also owns k=2048) ----
  float kreg[8];
#pragma unroll
  for (int jj = 0; jj < 8; ++jj) {
    int k = tid + 256 * jj;
    int ka = k & 2047, kb = (2048 - k) & 2047;
    float2 za = Zf[SWZ(pos2048(ka))];
    float2 zb = Zf[SWZ(pos2048(kb))];
    float her = 0.5f*(za.x+zb.x), hei = 0.5f*(za.y-zb.y);
    float hor = 0.5f*(za.y+zb.y), hoi = -0.5f*(za.x-zb.x);
    float sn, cs; __sincosf(-APACK * (float)k, &sn, &cs);
    float xr = her + cs*hor - sn*hoi;
    float xi = hei + cs*hoi + sn*hor;
    kreg[jj] = xr*xr + xi*xi;
  }
  float keyNy = 0.0f;
  if (tid == 0) { float2 z0 = Zf[SWZ(0)]; float v = z0.x - z0.y; keyNy = v*v; }

  // ---- radix select (4x8-bit) on fp32 key bits ----
  int kk = kptr[0];
  if (kk > 2049) kk = 2049;
  if (kk < 1) kk = 1;
  unsigned int prefix = 0u, pmask = 0u, Tkey = 0u;
  bool haveT = false;
  int R = kk;
#pragma unroll 1
  for (int p = 0; p < 4; ++p) {
    if (!haveT) {
      const int sh = 24 - 8 * p;
      hist[tid] = 0u;
      __syncthreads();
#pragma unroll
      for (int jj = 0; jj < 8; ++jj) {
        unsigned int u = __float_as_uint(kreg[jj]);
        if ((u & pmask) == prefix) atomicAdd(&hist[(u >> sh) & 255u], 1u);
      }
      if (tid == 0) {
        unsigned int u = __float_as_uint(keyNy);
        if ((u & pmask) == prefix) atomicAdd(&hist[(u >> sh) & 255u], 1u);
      }
      __syncthreads();
      if (tid < 64) {                     // single-wave suffix scan, 256 buckets
        int L = tid;
        int s0 = (int)hist[4*L], s1 = (int)hist[4*L+1];
        int s2 = (int)hist[4*L+2], s3 = (int)hist[4*L+3];
        int loc = s0 + s1 + s2 + s3;
        int suf = loc;
#pragma unroll
        for (int off = 1; off < 64; off <<= 1) {
          int t = __shfl(suf, (L + off) & 63, 64);
          suf += (L + off < 64) ? t : 0;
        }
        int e3 = suf - loc, i3 = e3 + s3;
        int e2 = i3,        i2 = e2 + s2;
        int e1 = i2,        i1 = e1 + s1;
        int e0 = i1,        i0 = e0 + s0;
        if (e3 < R && R <= i3) { bcD = 4*L+3; bcR = R - e3; bcCnt = s3; }
        if (e2 < R && R <= i2) { bcD = 4*L+2; bcR = R - e2; bcCnt = s2; }
        if (e1 < R && R <= i1) { bcD = 4*L+1; bcR = R - e1; bcCnt = s1; }
        if (e0 < R && R <= i0) { bcD = 4*L+0; bcR = R - e0; bcCnt = s0; }
      }
      __syncthreads();
      prefix |= (bcD << sh);
      pmask |= (255u << sh);
      R = (int)bcR;
      if (bcCnt == 1u) {
#pragma unroll
        for (int jj = 0; jj < 8; ++jj) {
          unsigned int u = __float_as_uint(kreg[jj]);
          if ((u & pmask) == prefix) bcT = u;
        }
        if (tid == 0) {
          unsigned int u = __float_as_uint(keyNy);
          if ((u & pmask) == prefix) bcT = u;
        }
        __syncthreads();
        Tkey = bcT;
        haveT = true;
      }
      __syncthreads();
    }
  }
  if (!haveT) Tkey = prefix;

  // ---- band around threshold; exact-fp64 recheck only if band is split ----
  float Tf = __uint_as_float(Tkey);
  float Thi = Tf * (1.0f + EPSB), Tlo = Tf * (1.0f - EPSB);
  if (tid == 0) { bcG = 0u; bcTieN = 0u; }
  __syncthreads();
#pragma unroll
  for (int jj = 0; jj < 8; ++jj) {
    float v = kreg[jj];
    if (v > Thi) atomicAdd(&bcG, 1u);
    else if (v >= Tlo) {
      int pos = (int)atomicAdd(&bcTieN, 1u);
      if (pos < 64) tieIdx[pos] = tid + 256 * jj;
    }
  }
  if (tid == 0) {
    float v = keyNy;
    if (v > Thi) atomicAdd(&bcG, 1u);
    else if (v >= Tlo) { int pos = (int)atomicAdd(&bcTieN, 1u); if (pos < 64) tieIdx[pos] = 2048; }
  }
  __syncthreads();
  int G = (int)bcG, E = (int)bcTieN, need = kk - G;

  if (need >= E) {   // common path: every band member kept
#pragma unroll
    for (int jj = 0; jj < 8; ++jj) maskA[tid + 256*jj] = (kreg[jj] >= Tlo) ? 1 : 0;
    if (tid == 0) maskA[2048] = (keyNy >= Tlo) ? 1 : 0;
    __syncthreads();
  } else {           // band split: exact fp64 DFT on candidates, top-k tie rules
#pragma unroll
    for (int jj = 0; jj < 8; ++jj) maskA[tid + 256*jj] = (kreg[jj] > Thi) ? 1 : 0;
    if (tid == 0) maskA[2048] = (keyNy > Thi) ? 1 : 0;
    __syncthreads();
    int nt = E < 64 ? E : 64;
    for (int ci = 0; ci < nt; ++ci) {
      int kq = tieIdx[ci];
      double sr = 0.0, si = 0.0;
#pragma unroll
      for (int j = 0; j < 16; ++j) {
        int m = (strideT == 1) ? (4*tid + 1024*(j>>2) + (j&3))
                               : (2*tid + 512*(j>>1) + (j&1));
        int a = (kq * m) & 4095;
        double ang = 1.5339807878856412e-3 * (double)a;   // 2*pi/4096 * a
        double sv, cv; sincos(ang, &sv, &cv);
        double xm = (double)xs[j];
        sr += xm * cv; si -= xm * sv;
      }
#pragma unroll
      for (int off = 1; off < 64; off <<= 1) {
        sr += __shfl_xor(sr, off); si += __shfl_xor(si, off);
      }
      if ((tid & 63) == 0) { cpR[tid >> 6] = sr; cpI[tid >> 6] = si; }
      __syncthreads();
      if (tid == 0) {
        double Rr = cpR[0]+cpR[1]+cpR[2]+cpR[3];
        double Ii = cpI[0]+cpI[1]+cpI[2]+cpI[3];
        candV[ci] = Rr*Rr + Ii*Ii;
      }
      __syncthreads();
    }
    if (tid == 0) {
      unsigned char* ch = (unsigned char*)hist;   // reuse (hist free now)
      for (int t = 0; t < nt; ++t) ch[t] = 0;
      int lim = need < nt ? need : nt;
      for (int s = 0; s < lim; ++s) {
        int best = -1;
        for (int t = 0; t < nt; ++t) {
          if (ch[t]) continue;
          if (best < 0 || candV[t] > candV[best] ||
              (candV[t] == candV[best] && tieIdx[t] < tieIdx[best])) best = t;
        }
        if (best >= 0) { ch[best] = 1; maskA[tieIdx[best]] = 1; }
      }
    }
    __syncthreads();
  }

  // ---- filter + repack Z'[k] (fp32), staged in registers ----
  float2 rz[8];
#pragma unroll
  for (int jj = 0; jj < 8; ++jj) {
    int k = tid + 256 * jj;
    int kb = (2048 - k) & 2047;
    float2 za = Zf[SWZ(pos2048(k))];
    float2 zb = Zf[SWZ(pos2048(kb))];
    float her = 0.5f*(za.x+zb.x), hei = 0.5f*(za.y-zb.y);
    float hor = 0.5f*(za.y+zb.y), hoi = -0.5f*(za.x-zb.x);
    float sn, cs; __sincosf(-APACK * (float)k, &sn, &cs);
    float wr = cs, wi = sn;
    float whr = wr*hor - wi*hoi, whi = wr*hoi + wi*hor;   // W*Ho
    float x1r = her + whr, x1i = hei + whi;               // X[k]
    float x2r = her - whr, x2i = -(hei - whi);            // X[2048-k]
    float Am = maskA[k] ? 1.0f : 0.0f, Bm = maskA[2048 - k] ? 1.0f : 0.0f;
    float Ar = Am*x1r, Ai = Am*x1i, Br = Bm*x2r, Bi = Bm*x2i;
    float sr_ = Ar + Br, si_ = Ai - Bi;
    float dr_ = Ar - Br, di_ = Ai + Bi;
    float tr_ = wr*dr_ + wi*di_, ti_ = wr*di_ - wi*dr_;   // conj(W)*(A-conj B)
    rz[jj] = make_float2(0.5f*(sr_ - ti_), 0.5f*(si_ + tr_));
  }
  __syncthreads();
#pragma unroll
  for (int jj = 0; jj < 8; ++jj) {
    int k = tid + 256 * jj;
    Zf[SWZ(pos2048(k))] = rz[jj];
  }
  __syncthreads();

  // ---- inverse FFT: radices [4,8,8,8], pos2048 -> natural order ----
#pragma unroll
  for (int h = 0; h < 2; ++h) {          // inverse radix-4
    int i0 = 4 * (tid + 256*h);
    float2 y0=Zf[SWZ(i0)], y1=Zf[SWZ(i0+1)], y2=Zf[SWZ(i0+2)], y3=Zf[SWZ(i0+3)];
    float2 f=cadd(y0,y2), e=csub(y0,y2), g=cadd(y1,y3), d=csub(y1,y3);
    float2 pd=cpi(d);
    Zf[SWZ(i0)]   = cadd(f,g);
    Zf[SWZ(i0+1)] = cadd(e,pd);
    Zf[SWZ(i0+2)] = csub(f,g);
    Zf[SWZ(i0+3)] = csub(e,pd);
  }
  __syncthreads();
  r8stage(Zf, 32*(tid>>2) + (tid&3), 4, A32 * (float)(tid&3), true);
  __syncthreads();
  r8stage(Zf, 256*(tid>>5) + (tid&31), 32, A256 * (float)(tid&31), true);
  __syncthreads();
  r8stage(Zf, tid, 256, A2048 * (float)tid, true);
  __syncthreads();

  // ---- store (scale 1/2048 for the unnormalized fwd/inv pair) ----
  const float scf = 1.0f / 2048.0f;
  if (strideT == 1) {
    float4* dp4 = reinterpret_cast<float4*>(dp);
#pragma unroll
    for (int it = 0; it < 4; ++it) {
      int t4 = tid + 256 * it;
      float2 v0 = Zf[SWZ(2*t4)], v1 = Zf[SWZ(2*t4+1)];
      dp4[t4] = make_float4(v0.x*scf, v0.y*scf, v1.x*scf, v1.y*scf);
    }
  } else {
#pragma unroll
    for (int it = 0; it < 8; ++it) {
      int n = tid + 256 * it;
      float2 v = Zf[SWZ(n)];
      dp[(size_t)(2*n) * strideT]   = v.x * scf;
      dp[(size_t)(2*n+1) * strideT] = v.y * scf;
    }
  }
}

extern "C" void kernel_launch(void* const* d_in, const int* in_sizes, int n_in,
                              void* d_out, int out_size, void* d_ws, size_t ws_size,
                              hipStream_t stream) {
  (void)in_sizes; (void)n_in; (void)out_size;
  const float* ts = (const float*)d_in[0];
  const int* kptr = (const int*)d_in[1];
  float* out = (float*)d_out;
  float* ws = (float*)d_ws;
  const int B = 64, S = 4096, C = 128;
  const size_t sigBytes = (size_t)B * S * C * sizeof(float);

  if (ws_size >= sigBytes) {
    // (B,S,C) -> (B,C,S) -> per-signal FFT/top-k in-place -> (B,S,C)
    tposeV<<<dim3(C / 64, S / 64, B), 256, 0, stream>>>(ts, ws, S, C);
    fourier_topk_kernel<<<B * C, TPB, 0, stream>>>(ws, ws, kptr, 1);
    tposeV<<<dim3(S / 64, C / 64, B), 256, 0, stream>>>(ws, out, C, S);
  } else {
    // Fallback: direct strided access (XCD-swizzled block->signal mapping).
    fourier_topk_kernel<<<B * C, TPB, 0, stream>>>(ts, out, kptr, C);
  }
}

// Round 5
// 432.021 us; speedup vs baseline: 1.4363x; 1.3960x over previous
//
#include <hip/hip_runtime.h>
#include <math.h>

#define TPB 256
// LDS swizzle at float2 (8B) granularity, bijective on [0,2048). For every
// wave access pattern in this kernel (strides 1,4,32,256 and the digit-
// reversed scatter) each bank-quad is hit exactly 4x per 64-lane b64 access,
// which is the conflict-free minimum (128 words over 32 banks).
#define SWZ(i) ((i) ^ (((i) >> 5) & 31) ^ ((i) >> 10))

// Angle constants
#define A2048 0.0030679615757712823f   // 2*pi/2048
#define A256  0.0245436926061702596f   // 2*pi/256
#define A32   0.1963495408493620774f   // 2*pi/32
#define APACK 0.0015339807878856411f   // pi/2048
#define EPSB  1.220703125e-4f          // 2^-13 selection band

__device__ __forceinline__ float2 cadd(float2 a, float2 b){return make_float2(a.x+b.x, a.y+b.y);}
__device__ __forceinline__ float2 csub(float2 a, float2 b){return make_float2(a.x-b.x, a.y-b.y);}
__device__ __forceinline__ float2 cmul(float2 a, float2 b){return make_float2(a.x*b.x-a.y*b.y, a.x*b.y+a.y*b.x);}
__device__ __forceinline__ float2 cni(float2 a){return make_float2(a.y, -a.x);}   // -i*a
__device__ __forceinline__ float2 cpi(float2 a){return make_float2(-a.y, a.x);}   // +i*a

// After DIF stages with radices [8,8,8,4], frequency k sits at pos2048(k).
__device__ __forceinline__ int pos2048(int k) {
  return 256*(k&7) + 32*((k>>3)&7) + 4*((k>>6)&7) + ((k>>9)&3);
}

__device__ __forceinline__ void fft8(float2 y[8]) {
  const float S2 = 0.70710678118654752f;
  float2 B0=cadd(y[0],y[4]), B4=csub(y[0],y[4]);
  float2 B1=cadd(y[1],y[5]), B5=csub(y[1],y[5]);
  float2 B2=cadd(y[2],y[6]), B6=csub(y[2],y[6]);
  float2 B3=cadd(y[3],y[7]), B7=csub(y[3],y[7]);
  float2 C0=cadd(B0,B2), C2=csub(B0,B2);
  float2 C1=cadd(B1,B3), C3=csub(B1,B3);
  float2 n6=cni(B6), n7=cni(B7);
  float2 C4=cadd(B4,n6), C6=csub(B4,n6);
  float2 C5=cadd(B5,n7), C7=csub(B5,n7);
  y[0]=cadd(C0,C1); y[4]=csub(C0,C1);
  float2 n3=cni(C3);
  y[2]=cadd(C2,n3); y[6]=csub(C2,n3);
  float2 t5=make_float2(S2*(C5.x+C5.y), S2*(C5.y-C5.x));       // w8*C5
  y[1]=cadd(C4,t5); y[5]=csub(C4,t5);
  float2 t7=make_float2(S2*(C7.y-C7.x), -S2*(C7.x+C7.y));      // w8^3*C7
  y[3]=cadd(C6,t7); y[7]=csub(C6,t7);
}

__device__ __forceinline__ void ifft8(float2 y[8]) {
  const float S2 = 0.70710678118654752f;
  float2 B0=cadd(y[0],y[4]), B4=csub(y[0],y[4]);
  float2 B1=cadd(y[1],y[5]), B5=csub(y[1],y[5]);
  float2 B2=cadd(y[2],y[6]), B6=csub(y[2],y[6]);
  float2 B3=cadd(y[3],y[7]), B7=csub(y[3],y[7]);
  float2 C0=cadd(B0,B2), C2=csub(B0,B2);
  float2 C1=cadd(B1,B3), C3=csub(B1,B3);
  float2 p6=cpi(B6), p7=cpi(B7);
  float2 C4=cadd(B4,p6), C6=csub(B4,p6);
  float2 C5=cadd(B5,p7), C7=csub(B5,p7);
  y[0]=cadd(C0,C1); y[4]=csub(C0,C1);
  float2 p3=cpi(C3);
  y[2]=cadd(C2,p3); y[6]=csub(C2,p3);
  float2 t5=make_float2(S2*(C5.x-C5.y), S2*(C5.x+C5.y));       // conj(w8)*C5
  y[1]=cadd(C4,t5); y[5]=csub(C4,t5);
  float2 t7=make_float2(-S2*(C7.x+C7.y), S2*(C7.x-C7.y));      // conj(w8)^3*C7
  y[3]=cadd(C6,t7); y[7]=csub(C6,t7);
}

// One radix-8 stage: DIF fwd = butterfly then twiddle W^(j*s); DIT inv =
// conj-twiddle then inverse butterfly. a1 carries the sign.
__device__ __forceinline__ void r8stage(float2* Zf, int idx0, int st, float a1, bool inv) {
  float2 y[8];
#pragma unroll
  for (int s=0;s<8;++s) y[s]=Zf[SWZ(idx0+st*s)];
  float sn, cs; __sincosf(a1, &sn, &cs);
  float2 w1=make_float2(cs,sn);
  float2 w2=cmul(w1,w1), w3=cmul(w2,w1), w4=cmul(w2,w2);
  float2 w5=cmul(w4,w1), w6=cmul(w4,w2), w7=cmul(w4,w3);
  if (inv){
    y[1]=cmul(y[1],w1); y[2]=cmul(y[2],w2); y[3]=cmul(y[3],w3);
    y[4]=cmul(y[4],w4); y[5]=cmul(y[5],w5); y[6]=cmul(y[6],w6); y[7]=cmul(y[7],w7);
    ifft8(y);
  } else {
    fft8(y);
    y[1]=cmul(y[1],w1); y[2]=cmul(y[2],w2); y[3]=cmul(y[3],w3);
    y[4]=cmul(y[4],w4); y[5]=cmul(y[5],w5); y[6]=cmul(y[6],w6); y[7]=cmul(y[7],w7);
  }
#pragma unroll
  for (int s=0;s<8;++s) Zf[SWZ(idx0+st*s)] = y[s];
}

// (B, R, Cd) -> (B, Cd, R) transpose, 64x64 tiles, float4 on both sides.
__global__ __launch_bounds__(256) void tposeV(const float* __restrict__ in,
                                              float* __restrict__ out,
                                              int R, int Cd) {
  __shared__ float tile[64][65];
  int t = threadIdx.x;
  int q = t & 15, r = t >> 4;
  int b = blockIdx.z;
  int c0 = blockIdx.x * 64, r0 = blockIdx.y * 64;
  const float4* in4 = reinterpret_cast<const float4*>(in + (size_t)b * R * Cd);
  float4* out4 = reinterpret_cast<float4*>(out + (size_t)b * R * Cd);
#pragma unroll
  for (int rr = r; rr < 64; rr += 16) {
    float4 v = in4[((size_t)(r0 + rr) * Cd + c0) / 4 + q];
    tile[rr][4 * q + 0] = v.x; tile[rr][4 * q + 1] = v.y;
    tile[rr][4 * q + 2] = v.z; tile[rr][4 * q + 3] = v.w;
  }
  __syncthreads();
#pragma unroll
  for (int cc = r; cc < 64; cc += 16) {
    float4 w;
    w.x = tile[4 * q + 0][cc]; w.y = tile[4 * q + 1][cc];
    w.z = tile[4 * q + 2][cc]; w.w = tile[4 * q + 3][cc];
    out4[((size_t)(c0 + cc) * R + r0) / 4 + q] = w;
  }
}

// One block per (b,c) signal: fp32 packed rfft (radix-8 register-resident) ->
// top-k via fp32 radix-select + band + exact fp64 DFT recheck -> fp32 irfft.
// No long-lived register arrays (R4's scratch-spill lesson): keys live in LDS,
// rare-path samples reloaded from global, repack is pairwise in-place.
__global__ __launch_bounds__(TPB, 4) void fourier_topk_kernel(
    const float* __restrict__ src, float* __restrict__ dst,
    const int* __restrict__ kptr, int strideT) {
  __shared__ float2 Zf[2048];            // 16 KB
  __shared__ float keyF[2049];           // 8.2 KB |X[k]|^2 keys
  __shared__ unsigned int hist[256];
  __shared__ unsigned char maskA[2052];
  __shared__ int tieIdx[64];
  __shared__ double candV[64];
  __shared__ double cpR[4], cpI[4];
  __shared__ unsigned int bcD, bcR, bcCnt, bcT, bcG, bcTieN;

  const int tid = threadIdx.x;
  int i = blockIdx.x;
  int xj = i & 7, mm = i >> 3;
  int c = 16 * xj + (mm & 15);
  int b = mm >> 4;
  const size_t base = (strideT == 1) ? ((size_t)(b * 128 + c)) * 4096
                                     : ((size_t)b * 4096 * 128 + (size_t)c);
  const float* sp = src + base;
  float* dp = dst + base;

  // ---- load to LDS only (no register copy) ----
  if (strideT == 1) {
    const float4* sp4 = reinterpret_cast<const float4*>(sp);
#pragma unroll
    for (int it = 0; it < 4; ++it) {
      int t4 = tid + 256 * it;
      float4 v = sp4[t4];
      Zf[SWZ(2*t4)]   = make_float2(v.x, v.y);
      Zf[SWZ(2*t4+1)] = make_float2(v.z, v.w);
    }
  } else {
#pragma unroll
    for (int it = 0; it < 8; ++it) {
      int n = tid + 256 * it;
      float a = sp[(size_t)(2*n) * strideT];
      float bb = sp[(size_t)(2*n+1) * strideT];
      Zf[SWZ(n)] = make_float2(a, bb);
    }
  }
  __syncthreads();

  // ---- forward FFT: radices [8,8,8,4], natural -> pos2048 order ----
  r8stage(Zf, tid, 256, -A2048 * (float)tid, false);
  __syncthreads();
  r8stage(Zf, 256*(tid>>5) + (tid&31), 32, -A256 * (float)(tid&31), false);
  __syncthreads();
  r8stage(Zf, 32*(tid>>2) + (tid&3), 4, -A32 * (float)(tid&3), false);
  __syncthreads();
#pragma unroll
  for (int h = 0; h < 2; ++h) {          // final radix-4, no twiddle
    int i0 = 4 * (tid + 256*h);
    float2 A0=Zf[SWZ(i0)], A1=Zf[SWZ(i0+1)], A2=Zf[SWZ(i0+2)], A3=Zf[SWZ(i0+3)];
    float2 f=cadd(A0,A2), e=csub(A0,A2), g=cadd(A1,A3), d=csub(A1,A3);
    float2 nd=cni(d);
    Zf[SWZ(i0)]   = cadd(f,g);
    Zf[SWZ(i0+1)] = cadd(e,nd);
    Zf[SWZ(i0+2)] = csub(f,g);
    Zf[SWZ(i0+3)] = csub(e,nd);
  }
  __syncthreads();

  // ---- keys to LDS, pairwise: one unpack -> |X[k]|^2 and |X[2048-k]|^2 ----
#pragma unroll
  for (int jj = 0; jj < 4; ++jj) {
    int k = tid + 256 * jj;                       // k in [0,1024)
    float2 za = Zf[SWZ(pos2048(k))];
    float2 zb = Zf[SWZ(pos2048((2048 - k) & 2047))];
    float her = 0.5f*(za.x+zb.x), hei = 0.5f*(za.y-zb.y);
    float hor = 0.5f*(za.y+zb.y), hoi = -0.5f*(za.x-zb.x);
    float sn, cs; __sincosf(-APACK * (float)k, &sn, &cs);
    float whr = cs*hor - sn*hoi, whi = cs*hoi + sn*hor;
    float x1r = her + whr, x1i = hei + whi;       // X[k]
    float x2r = her - whr, x2i = whi - hei;       // X[2048-k]
    keyF[k]        = x1r*x1r + x1i*x1i;
    keyF[2048 - k] = x2r*x2r + x2i*x2i;           // k=0 -> keyF[2048] (Nyquist)
  }
  if (tid == 0) {                                 // k = 1024 (self-paired)
    float2 za = Zf[SWZ(pos2048(1024))];
    keyF[1024] = za.x*za.x + za.y*za.y;
  }
  __syncthreads();

  // ---- radix select (4x8-bit) on fp32 key bits ----
  int kk = kptr[0];
  if (kk > 2049) kk = 2049;
  if (kk < 1) kk = 1;
  unsigned int prefix = 0u, pmask = 0u, Tkey = 0u;
  bool haveT = false;
  int R = kk;
#pragma unroll 1
  for (int p = 0; p < 4; ++p) {
    if (!haveT) {
      const int sh = 24 - 8 * p;
      hist[tid] = 0u;
      __syncthreads();
      for (int k = tid; k <= 2048; k += TPB) {
        unsigned int u = __float_as_uint(keyF[k]);
        if ((u & pmask) == prefix) atomicAdd(&hist[(u >> sh) & 255u], 1u);
      }
      __syncthreads();
      if (tid < 64) {                     // single-wave suffix scan, 256 buckets
        int L = tid;
        int s0 = (int)hist[4*L], s1 = (int)hist[4*L+1];
        int s2 = (int)hist[4*L+2], s3 = (int)hist[4*L+3];
        int loc = s0 + s1 + s2 + s3;
        int suf = loc;
#pragma unroll
        for (int off = 1; off < 64; off <<= 1) {
          int t = __shfl(suf, (L + off) & 63, 64);
          suf += (L + off < 64) ? t : 0;
        }
        int e3 = suf - loc, i3 = e3 + s3;
        int e2 = i3,        i2 = e2 + s2;
        int e1 = i2,        i1 = e1 + s1;
        int e0 = i1,        i0 = e0 + s0;
        if (e3 < R && R <= i3) { bcD = 4*L+3; bcR = R - e3; bcCnt = s3; }
        if (e2 < R && R <= i2) { bcD = 4*L+2; bcR = R - e2; bcCnt = s2; }
        if (e1 < R && R <= i1) { bcD = 4*L+1; bcR = R - e1; bcCnt = s1; }
        if (e0 < R && R <= i0) { bcD = 4*L+0; bcR = R - e0; bcCnt = s0; }
      }
      __syncthreads();
      prefix |= (bcD << sh);
      pmask |= (255u << sh);
      R = (int)bcR;
      if (bcCnt == 1u) {
        for (int k = tid; k <= 2048; k += TPB) {
          unsigned int u = __float_as_uint(keyF[k]);
          if ((u & pmask) == prefix) bcT = u;
        }
        __syncthreads();
        Tkey = bcT;
        haveT = true;
      }
      __syncthreads();
    }
  }
  if (!haveT) Tkey = prefix;

  // ---- band around threshold; exact-fp64 recheck only if band is split ----
  float Tf = __uint_as_float(Tkey);
  float Thi = Tf * (1.0f + EPSB), Tlo = Tf * (1.0f - EPSB);
  if (tid == 0) { bcG = 0u; bcTieN = 0u; }
  __syncthreads();
  for (int k = tid; k <= 2048; k += TPB) {
    float v = keyF[k];
    if (v > Thi) atomicAdd(&bcG, 1u);
    else if (v >= Tlo) {
      int pos = (int)atomicAdd(&bcTieN, 1u);
      if (pos < 64) tieIdx[pos] = k;
    }
  }
  __syncthreads();
  int G = (int)bcG, E = (int)bcTieN, need = kk - G;

  if (need >= E) {   // common path: every band member kept
    for (int k = tid; k <= 2048; k += TPB)
      maskA[k] = (keyF[k] >= Tlo) ? 1 : 0;
    __syncthreads();
  } else {           // band split: exact fp64 DFT on candidates (reload input)
    for (int k = tid; k <= 2048; k += TPB)
      maskA[k] = (keyF[k] > Thi) ? 1 : 0;
    __syncthreads();
    int nt = E < 64 ? E : 64;
    for (int ci = 0; ci < nt; ++ci) {
      int kq = tieIdx[ci];
      double sr = 0.0, si = 0.0;
#pragma unroll 1
      for (int j = 0; j < 16; ++j) {
        int m = tid + 256 * j;
        double xm = (double)sp[(size_t)m * strideT];   // src intact (dst written later)
        int a = (kq * m) & 4095;
        double ang = 1.5339807878856412e-3 * (double)a;   // 2*pi/4096 * a
        double sv, cv; sincos(ang, &sv, &cv);
        sr += xm * cv; si -= xm * sv;
      }
#pragma unroll
      for (int off = 1; off < 64; off <<= 1) {
        sr += __shfl_xor(sr, off); si += __shfl_xor(si, off);
      }
      if ((tid & 63) == 0) { cpR[tid >> 6] = sr; cpI[tid >> 6] = si; }
      __syncthreads();
      if (tid == 0) {
        double Rr = cpR[0]+cpR[1]+cpR[2]+cpR[3];
        double Ii = cpI[0]+cpI[1]+cpI[2]+cpI[3];
        candV[ci] = Rr*Rr + Ii*Ii;
      }
      __syncthreads();
    }
    if (tid == 0) {
      unsigned char* ch = (unsigned char*)hist;   // reuse (hist free now)
      for (int t = 0; t < nt; ++t) ch[t] = 0;
      int lim = need < nt ? need : nt;
      for (int s = 0; s < lim; ++s) {
        int best = -1;
        for (int t = 0; t < nt; ++t) {
          if (ch[t]) continue;
          if (best < 0 || candV[t] > candV[best] ||
              (candV[t] == candV[best] && tieIdx[t] < tieIdx[best])) best = t;
        }
        if (best >= 0) { ch[best] = 1; maskA[tieIdx[best]] = 1; }
      }
    }
    __syncthreads();
  }

  // ---- filter + repack, PAIRWISE IN-PLACE (thread-local pairs, no barrier):
  // pair (k, 2048-k) reads exactly {Zf[pos(k)], Zf[pos(2048-k)]} and writes
  // the same two slots. Z'[2048-k] = 0.5(sr+ti, tr-si) from k's intermediates.
#pragma unroll
  for (int jj = 0; jj < 4; ++jj) {
    int k = tid + 256 * jj;
    if (k == 0) {                                 // k=0 and k=1024 specials
      int p0 = SWZ(pos2048(0));
      float2 z0 = Zf[p0];
      float X0 = z0.x + z0.y, XN = z0.x - z0.y;
      float A = maskA[0] ? X0 : 0.0f, Bv = maskA[2048] ? XN : 0.0f;
      Zf[p0] = make_float2(0.5f*(A + Bv), 0.5f*(A - Bv));
      int p1 = SWZ(pos2048(1024));
      float2 z1 = Zf[p1];
      float m1 = maskA[1024] ? 1.0f : 0.0f;
      Zf[p1] = make_float2(m1 * z1.x, m1 * z1.y);
    } else {                                      // k in [1,1024)
      int pa = SWZ(pos2048(k)), pb = SWZ(pos2048(2048 - k));
      float2 za = Zf[pa], zb = Zf[pb];
      float her = 0.5f*(za.x+zb.x), hei = 0.5f*(za.y-zb.y);
      float hor = 0.5f*(za.y+zb.y), hoi = -0.5f*(za.x-zb.x);
      float sn, cs; __sincosf(-APACK * (float)k, &sn, &cs);
      float wr = cs, wi = sn;
      float whr = wr*hor - wi*hoi, whi = wr*hoi + wi*hor;
      float x1r = her + whr, x1i = hei + whi;     // X[k]
      float x2r = her - whr, x2i = whi - hei;     // X[2048-k]
      float mA = maskA[k] ? 1.0f : 0.0f, mB = maskA[2048 - k] ? 1.0f : 0.0f;
      float Ar = mA*x1r, Ai = mA*x1i, Br = mB*x2r, Bi = mB*x2i;
      float sr = Ar + Br, si = Ai - Bi;
      float dr = Ar - Br, di = Ai + Bi;
      float tr = wr*dr + wi*di, ti = wr*di - wi*dr;   // conj(W)*d
      Zf[pa] = make_float2(0.5f*(sr - ti), 0.5f*(si + tr));
      Zf[pb] = make_float2(0.5f*(sr + ti), 0.5f*(tr - si));
    }
  }
  __syncthreads();

  // ---- inverse FFT: radices [4,8,8,8], pos2048 -> natural order ----
#pragma unroll
  for (int h = 0; h < 2; ++h) {          // inverse radix-4
    int i0 = 4 * (tid + 256*h);
    float2 y0=Zf[SWZ(i0)], y1=Zf[SWZ(i0+1)], y2=Zf[SWZ(i0+2)], y3=Zf[SWZ(i0+3)];
    float2 f=cadd(y0,y2), e=csub(y0,y2), g=cadd(y1,y3), d=csub(y1,y3);
    float2 pd=cpi(d);
    Zf[SWZ(i0)]   = cadd(f,g);
    Zf[SWZ(i0+1)] = cadd(e,pd);
    Zf[SWZ(i0+2)] = csub(f,g);
    Zf[SWZ(i0+3)] = csub(e,pd);
  }
  __syncthreads();
  r8stage(Zf, 32*(tid>>2) + (tid&3), 4, A32 * (float)(tid&3), true);
  __syncthreads();
  r8stage(Zf, 256*(tid>>5) + (tid&31), 32, A256 * (float)(tid&31), true);
  __syncthreads();
  r8stage(Zf, tid, 256, A2048 * (float)tid, true);
  __syncthreads();

  // ---- store (scale 1/2048 for the unnormalized fwd/inv pair) ----
  const float scf = 1.0f / 2048.0f;
  if (strideT == 1) {
    float4* dp4 = reinterpret_cast<float4*>(dp);
#pragma unroll
    for (int it = 0; it < 4; ++it) {
      int t4 = tid + 256 * it;
      float2 v0 = Zf[SWZ(2*t4)], v1 = Zf[SWZ(2*t4+1)];
      dp4[t4] = make_float4(v0.x*scf, v0.y*scf, v1.x*scf, v1.y*scf);
    }
  } else {
#pragma unroll
    for (int it = 0; it < 8; ++it) {
      int n = tid + 256 * it;
      float2 v = Zf[SWZ(n)];
      dp[(size_t)(2*n) * strideT]   = v.x * scf;
      dp[(size_t)(2*n+1) * strideT] = v.y * scf;
    }
  }
}

extern "C" void kernel_launch(void* const* d_in, const int* in_sizes, int n_in,
                              void* d_out, int out_size, void* d_ws, size_t ws_size,
                              hipStream_t stream) {
  (void)in_sizes; (void)n_in; (void)out_size;
  const float* ts = (const float*)d_in[0];
  const int* kptr = (const int*)d_in[1];
  float* out = (float*)d_out;
  float* ws = (float*)d_ws;
  const int B = 64, S = 4096, C = 128;
  const size_t sigBytes = (size_t)B * S * C * sizeof(float);

  if (ws_size >= sigBytes) {
    // (B,S,C) -> (B,C,S) -> per-signal FFT/top-k in-place -> (B,S,C)
    tposeV<<<dim3(C / 64, S / 64, B), 256, 0, stream>>>(ts, ws, S, C);
    fourier_topk_kernel<<<B * C, TPB, 0, stream>>>(ws, ws, kptr, 1);
    tposeV<<<dim3(S / 64, C / 64, B), 256, 0, stream>>>(ws, out, C, S);
  } else {
    // Fallback: direct strided access (XCD-swizzled block->signal mapping).
    fourier_topk_kernel<<<B * C, TPB, 0, stream>>>(ts, out, kptr, C);
  }
}